// Round 10
// baseline (1194.117 us; speedup 1.0000x reference)
//
#include <hip/hip_runtime.h>
#include <stdint.h>

// Problem constants
#define BB 2
#define TT 2048
#define DD 2048
#define HH 16
#define HD 2048     // H*Dk = H*Dv
#define MM 4096     // B*T
#define SCH 16      // scan chunk steps

typedef float f32x4 __attribute__((ext_vector_type(4)));
typedef __bf16 bf16x8 __attribute__((ext_vector_type(8)));
typedef unsigned short u16x4 __attribute__((ext_vector_type(4)));
typedef unsigned int u32x4 __attribute__((ext_vector_type(4)));

__device__ __forceinline__ unsigned short f2b(float f) {
  unsigned int u = __float_as_uint(f);
  u += 0x7FFFu + ((u >> 16) & 1u);   // RNE
  return (unsigned short)(u >> 16);
}

// unpack 8 bf16 (as u32x4) -> two f32x4 in natural channel order
__device__ __forceinline__ void unpack8(u32x4 r, f32x4& lo, f32x4& hi) {
  lo[0] = __uint_as_float(r[0] << 16); lo[1] = __uint_as_float(r[0] & 0xffff0000u);
  lo[2] = __uint_as_float(r[1] << 16); lo[3] = __uint_as_float(r[1] & 0xffff0000u);
  hi[0] = __uint_as_float(r[2] << 16); hi[1] = __uint_as_float(r[2] & 0xffff0000u);
  hi[2] = __uint_as_float(r[3] << 16); hi[3] = __uint_as_float(r[3] & 0xffff0000u);
}

__device__ __forceinline__ void async_ld16(const void* g, void* l) {
  typedef __attribute__((address_space(3))) void as3_t;
  typedef const __attribute__((address_space(1))) void as1_t;
  // NOTE: LDS arg must be WAVE-UNIFORM base; HW adds lane*16 itself.
  __builtin_amdgcn_global_load_lds((as1_t*)(uintptr_t)g,
                                   (as3_t*)(unsigned int)(uintptr_t)l, 16, 0, 0);
}

// ---- DPP 16-lane all-reduce (VALU-pipe). r6 lesson: BUILTIN form only ----
template <int CTRL>
__device__ __forceinline__ float dpp_add(float x) {
  int y = __builtin_amdgcn_update_dpp(0, __float_as_int(x), CTRL, 0xF, 0xF, false);
  return x + __int_as_float(y);
}
__device__ __forceinline__ float reduce16(float x) {
  x = dpp_add<0xB1>(x);    // quad_perm [1,0,3,2]
  x = dpp_add<0x4E>(x);    // quad_perm [2,3,0,1]
  x = dpp_add<0x124>(x);   // row_ror:4
  x = dpp_add<0x128>(x);   // row_ror:8
  return x;
}

// ---------------- cast f32 -> bf16 (vectorized x4) ----------------
__global__ __launch_bounds__(256) void cast_f32_bf16(const float* __restrict__ in,
                                                     unsigned short* __restrict__ out,
                                                     int n4) {
  int i = blockIdx.x * 256 + threadIdx.x;
  if (i >= n4) return;
  f32x4 v = *(const f32x4*)(in + (size_t)i * 4);
  u16x4 r;
  #pragma unroll
  for (int j = 0; j < 4; j++) r[j] = f2b(v[j]);
  *(u16x4*)(out + (size_t)i * 4) = r;
}

// ---------------- transpose + cast: in f32 [R,C] -> out bf16 [C,R] ----------------
__global__ __launch_bounds__(256) void transpose_cast(const float* __restrict__ in,
                                                      unsigned short* __restrict__ out,
                                                      int R, int C) {
  __shared__ float tile[32][33];
  int bx = blockIdx.x * 32, by = blockIdx.y * 32;
  int tx = threadIdx.x, ty = threadIdx.y;
  #pragma unroll
  for (int i = 0; i < 32; i += 8)
    tile[ty + i][tx] = in[(size_t)(by + ty + i) * C + bx + tx];
  __syncthreads();
  #pragma unroll
  for (int i = 0; i < 32; i += 8)
    out[(size_t)(bx + ty + i) * R + by + tx] = f2b(tile[tx][ty + i]);
}

// ---------------- shared GEMM core: 128x128 tile, bf16 MFMA, XCD tile remap ----------------
#define GEMM_PROLOGUE_AND_LOOP                                                         \
  __shared__ __align__(16) unsigned short As[128 * 32];                                \
  __shared__ __align__(16) unsigned short Bs[128 * 32];                                \
  int tid = threadIdx.x;                                                               \
  int l = tid & 63, w = tid >> 6;                                                      \
  int nbx = gridDim.x;                                                                 \
  int tot = nbx * gridDim.y;                                                           \
  int id = blockIdx.y * nbx + blockIdx.x;                                              \
  int nid = id;                                                                        \
  if ((tot & 7) == 0) { int per = tot >> 3; nid = (id & 7) * per + (id >> 3); }        \
  int row0 = (nid / nbx) * 128, col0 = (nid % nbx) * 128;                              \
  int wm = (w >> 1) * 64, wn = (w & 1) * 64;                                           \
  const f32x4 fz = {0.f, 0.f, 0.f, 0.f};                                               \
  f32x4 acc[4][4];                                                                     \
  _Pragma("unroll") for (int i = 0; i < 4; i++)                                        \
    _Pragma("unroll") for (int j = 0; j < 4; j++) acc[i][j] = fz;                      \
  int srow = l >> 2, skoff = (l & 3) * 8;                                              \
  int quad = l >> 4, mrow = l & 15;                                                    \
  for (int kt = 0; kt < K; kt += 32) {                                                 \
    _Pragma("unroll") for (int i = 0; i < 2; i++) {                                    \
      int c = w * 2 + i;                                                               \
      const unsigned short* gA = A + (size_t)(row0 + c * 16 + srow) * K + kt + skoff;  \
      const unsigned short* gB = Bt + (size_t)(col0 + c * 16 + srow) * K + kt + skoff; \
      async_ld16(gA, As + c * 512);                                                    \
      async_ld16(gB, Bs + c * 512);                                                    \
    }                                                                                  \
    __syncthreads();                                                                   \
    bf16x8 af[4], bfr[4];                                                              \
    _Pragma("unroll") for (int i = 0; i < 4; i++)                                      \
      af[i] = *(const bf16x8*)(As + (wm + i * 16 + mrow) * 32 + quad * 8);             \
    _Pragma("unroll") for (int j = 0; j < 4; j++)                                      \
      bfr[j] = *(const bf16x8*)(Bs + (wn + j * 16 + mrow) * 32 + quad * 8);            \
    _Pragma("unroll") for (int i = 0; i < 4; i++)                                      \
      _Pragma("unroll") for (int j = 0; j < 4; j++)                                    \
        acc[i][j] = __builtin_amdgcn_mfma_f32_16x16x32_bf16(af[i], bfr[j], acc[i][j],  \
                                                            0, 0, 0);                  \
    __syncthreads();                                                                   \
  }

// ---- variant 1: f32 output, optional bias (row layout) ----
__global__ __launch_bounds__(256) void gemm_bf16(const unsigned short* __restrict__ A,
                                                 const unsigned short* __restrict__ Bt,
                                                 float* __restrict__ C,
                                                 const float* __restrict__ bias,
                                                 int M, int N, int K) {
  GEMM_PROLOGUE_AND_LOOP
  #pragma unroll
  for (int i = 0; i < 4; i++)
    #pragma unroll
    for (int j = 0; j < 4; j++)
      #pragma unroll
      for (int r = 0; r < 4; r++) {
        int rr = row0 + wm + i * 16 + quad * 4 + r;
        int cc = col0 + wn + j * 16 + mrow;
        float v = acc[i][j][r];
        if (bias) v += bias[cc];
        C[(size_t)rr * N + cc] = v;
      }
}

// ---- variant 2: fused q|k|v|gate (N=8192), bf16 outputs ----
// sub = cc>>11: 0,1,2 -> scan layout [B,H,T,128]; 3 -> gate, row layout + bias.
// sub and h are uniform per tile (col0 multiple of 128).
__global__ __launch_bounds__(256) void gemm_qkvg(const unsigned short* __restrict__ A,
                                                 const unsigned short* __restrict__ Bt,
                                                 unsigned short* __restrict__ Dq,
                                                 unsigned short* __restrict__ Dk,
                                                 unsigned short* __restrict__ Dv,
                                                 unsigned short* __restrict__ Dg,
                                                 const float* __restrict__ bg,
                                                 int M, int N, int K) {
  GEMM_PROLOGUE_AND_LOOP
  #pragma unroll
  for (int i = 0; i < 4; i++)
    #pragma unroll
    for (int j = 0; j < 4; j++)
      #pragma unroll
      for (int r = 0; r < 4; r++) {
        int rr = row0 + wm + i * 16 + quad * 4 + r;
        int cc = col0 + wn + j * 16 + mrow;
        int sub = cc >> 11;
        int ch = cc & (HD - 1);
        int b = rr >> 11, t = rr & (TT - 1);
        if (sub == 3) {
          Dg[(size_t)rr * HD + ch] = f2b(acc[i][j][r] + bg[ch]);
        } else {
          int h = ch >> 7, c2 = ch & 127;
          unsigned short* dst = (sub == 0) ? Dq : (sub == 1) ? Dk : Dv;
          dst[(((size_t)(b * HH + h)) * TT + t) * 128 + c2] = f2b(acc[i][j][r]);
        }
      }
}

// ---- variant 3: Wf2 GEMM with gexp fused into the epilogue -> f32 scan layout ----
// ge = exp(-exp(A_log[h]) * softplus(acc + dt_bias)); h uniform per tile.
__global__ __launch_bounds__(256) void gemm_gexp(const unsigned short* __restrict__ A,
                                                 const unsigned short* __restrict__ Bt,
                                                 float* __restrict__ GE,
                                                 const float* __restrict__ A_log,
                                                 const float* __restrict__ dt_bias,
                                                 int M, int N, int K) {
  GEMM_PROLOGUE_AND_LOOP
  int h = col0 >> 7;
  float Ae = expf(A_log[h]);
  #pragma unroll
  for (int i = 0; i < 4; i++)
    #pragma unroll
    for (int j = 0; j < 4; j++)
      #pragma unroll
      for (int r = 0; r < 4; r++) {
        int rr = row0 + wm + i * 16 + quad * 4 + r;
        int cc = col0 + wn + j * 16 + mrow;
        int b = rr >> 11, t = rr & (TT - 1);
        int c2 = cc & 127;
        float gv = acc[i][j][r] + dt_bias[cc];
        float sp = (gv > 20.f) ? gv : log1pf(expf(gv));
        GE[(((size_t)(b * HH + h)) * TT + t) * 128 + c2] = expf(-Ae * sp);
      }
}

// ---------------- causal depthwise conv(K=4) + SiLU (+ per-head l2norm) ----------------
// Input: bf16 scan layout. Output: bf16 (obf16=1, for q,k) or f32 (for v), scan layout.
__global__ __launch_bounds__(256) void conv_silu_kernel(const unsigned short* __restrict__ Pre,
                                                        const float* __restrict__ cw,
                                                        void* __restrict__ outp,
                                                        int do_norm, float post_mul,
                                                        int obf16) {
  int bt = blockIdx.x;
  int b = bt >> 11, t = bt & (TT - 1);
  int tid = threadIdx.x;
  int ch0 = tid * 8;
  int h = tid >> 4, c0 = (tid & 15) * 8;
  f32x4 wv[8];
  #pragma unroll
  for (int j = 0; j < 8; j++) wv[j] = *(const f32x4*)(cw + (size_t)(ch0 + j) * 4);
  float acc[8] = {0, 0, 0, 0, 0, 0, 0, 0};
  const unsigned short* base = Pre + (((size_t)(b * HH + h)) * TT) * 128 + c0;
  #pragma unroll
  for (int i = 0; i < 4; i++) {
    int tt = t - 3 + i;
    if (tt < 0) continue;
    u32x4 raw = *(const u32x4*)(base + (size_t)tt * 128);
    float e[8];
    #pragma unroll
    for (int jj = 0; jj < 4; jj++) {
      e[2 * jj]     = __uint_as_float(raw[jj] << 16);
      e[2 * jj + 1] = __uint_as_float(raw[jj] & 0xffff0000u);
    }
    #pragma unroll
    for (int j = 0; j < 8; j++) acc[j] += e[j] * wv[j][i];
  }
  float val[8];
  #pragma unroll
  for (int j = 0; j < 8; j++) val[j] = acc[j] / (1.f + expf(-acc[j]));   // SiLU
  if (do_norm) {
    float ss = 0.f;
    #pragma unroll
    for (int j = 0; j < 8; j++) ss += val[j] * val[j];
    ss = reduce16(ss);
    float rs = rsqrtf(ss + 1e-6f) * post_mul;
    #pragma unroll
    for (int j = 0; j < 8; j++) val[j] *= rs;
  }
  size_t idx = (((size_t)(b * HH + h)) * TT + t) * 128 + c0;
  if (obf16) {
    unsigned short* op = (unsigned short*)outp + idx;
    u16x4 r0, r1;
    #pragma unroll
    for (int j = 0; j < 4; j++) { r0[j] = f2b(val[j]); r1[j] = f2b(val[4 + j]); }
    *(u16x4*)op = r0;
    *(u16x4*)(op + 4) = r1;
  } else {
    float* op = (float*)outp + idx;
    f32x4 o0, o1;
    #pragma unroll
    for (int j = 0; j < 4; j++) { o0[j] = val[j]; o1[j] = val[4 + j]; }
    *(f32x4*)op = o0;
    *(f32x4*)(op + 4) = o1;
  }
}

// ---------------- beta = sigmoid(x @ Wb) -> [B,H,T] layout ----------------
__global__ __launch_bounds__(256) void beta_kernel(const float* __restrict__ x,
                                                   const float* __restrict__ Wb,
                                                   float* __restrict__ beta) {
  __shared__ float xs[2048];
  int bt = blockIdx.x, tid = threadIdx.x;
  int b = bt >> 11, t = bt & (TT - 1);
  const float* row = x + (size_t)bt * DD;
  #pragma unroll
  for (int i = 0; i < 2; i++)
    *(f32x4*)(xs + tid * 8 + i * 4) = *(const f32x4*)(row + tid * 8 + i * 4);
  __syncthreads();
  int h = tid >> 4, seg = tid & 15;
  float p = 0.f;
  for (int j = 0; j < 128; j++) {
    int d = seg * 128 + ((j + seg * 9) & 127);
    p += xs[d] * Wb[(size_t)d * HH + h];
  }
  p = reduce16(p);
  if (seg == 0) beta[((size_t)(b * HH + h)) * TT + t] = 1.f / (1.f + expf(-p));
}

// ---------------- KDA delta-rule scan: bf16 q/k in LDS, 2-copy duplication ----------------
// LDS pipe was the co-limiter (68% busy at 6 b128/step/wave). q,k now bf16:
// one b128 per operand per step (4 total with g's two). Conflict rule
// (measured r2/r4): 32-distinct-16B-units @ 2-fold multiplicity = free;
// 16-distinct @ 4-fold costs +4cyc/read. Fix: TWO LDS copies of each stream;
// groups 0,2 read copy0, groups 1,3 read copy1 -> 32 distinct units @ 2-fold.
// Natural channel order everywhere (parity machinery deleted). g,v stay f32
// (decay precision compounds over 2048 steps; q,k are l2-normed, bf16-safe).
// Staging (async, hidden): w0/w1 -> g copy0/copy1, w2 -> k both, w3 -> q both + v.
// bh=blk&31 XCD mapping (L2 dedup). o overlays dead B1/B2 region (no v alias).
__global__ __launch_bounds__(256, 1) void scan_kernel(const unsigned short* __restrict__ q,
                                                      const unsigned short* __restrict__ k,
                                                      const float* __restrict__ v,
                                                      const float* __restrict__ ge,
                                                      const float* __restrict__ beta,
                                                      float* __restrict__ o) {
  __shared__ __align__(16) float gbuf[2][2 * SCH * 128];           // 32 KB
  __shared__ __align__(16) unsigned short kbuf[2][2 * SCH * 128];  // 16 KB
  __shared__ __align__(16) unsigned short qbuf[2][2 * SCH * 128];  // 16 KB
  __shared__ __align__(16) float vbuf[2][SCH * 16];                //  2 KB
  __shared__ __align__(16) float bbuf[TT];                         //  8 KB

  int blk = blockIdx.x;
  int bh = blk & 31;
  int colblk = blk >> 5;
  int tid = threadIdx.x;
  int w = tid >> 6, l = tid & 63;
  int grp = l >> 4, i = l & 15;
  int lcol = w * 4 + grp;
  int col = colblk * 16 + lcol;
  int copy = grp & 1;

  const unsigned short* kbh = k + (size_t)bh * TT * 128;
  const unsigned short* qbh = q + (size_t)bh * TT * 128;
  const float* gbh = ge + (size_t)bh * TT * 128;
  const float* vbh = v + (size_t)bh * TT * 128;
  const float* bbh = beta + (size_t)bh * TT;
  float* obh = o + (size_t)bh * TT * 128;

  // stage whole beta sequence (8 KB) once
  #pragma unroll
  for (int j = 0; j < 2; j++) {
    int jj = w * 2 + j;
    async_ld16(bbh + jj * 256 + l * 4, (float*)bbuf + jj * 256);
  }
  auto stage = [&](int cidx, int nb) {
    size_t t0 = (size_t)cidx * SCH;
    if (w == 0) {
      #pragma unroll
      for (int j = 0; j < 8; j++)
        async_ld16(gbh + t0 * 128 + j * 256 + l * 4, (float*)gbuf[nb] + j * 256);
    } else if (w == 1) {
      #pragma unroll
      for (int j = 0; j < 8; j++)
        async_ld16(gbh + t0 * 128 + j * 256 + l * 4,
                   (float*)gbuf[nb] + SCH * 128 + j * 256);
    } else if (w == 2) {
      #pragma unroll
      for (int j = 0; j < 4; j++)
        async_ld16(kbh + t0 * 128 + j * 512 + l * 8,
                   (unsigned short*)kbuf[nb] + j * 512);
      #pragma unroll
      for (int j = 0; j < 4; j++)
        async_ld16(kbh + t0 * 128 + j * 512 + l * 8,
                   (unsigned short*)kbuf[nb] + SCH * 128 + j * 512);
    } else {
      #pragma unroll
      for (int j = 0; j < 4; j++)
        async_ld16(qbh + t0 * 128 + j * 512 + l * 8,
                   (unsigned short*)qbuf[nb] + j * 512);
      #pragma unroll
      for (int j = 0; j < 4; j++)
        async_ld16(qbh + t0 * 128 + j * 512 + l * 8,
                   (unsigned short*)qbuf[nb] + SCH * 128 + j * 512);
      async_ld16(vbh + (t0 + (size_t)(l >> 2)) * 128 + colblk * 16 + (l & 3) * 4,
                 (float*)vbuf[nb]);
    }
  };
  stage(0, 0);
  __syncthreads();

  f32x4 s0 = {0.f, 0.f, 0.f, 0.f}, s1 = {0.f, 0.f, 0.f, 0.f};
  float okeep = 0.f;

  for (int c = 0; c < TT / SCH; c++) {
    int cb = c & 1, nb = cb ^ 1;
    if (c + 1 < TT / SCH) stage(c + 1, nb);

    const unsigned short* kcp = kbuf[cb] + copy * (SCH * 128);
    const unsigned short* qcp = qbuf[cb] + copy * (SCH * 128);
    const float* gcp = gbuf[cb] + copy * (SCH * 128);

    // per-chunk preload: v*beta and beta into registers
    float vbt[SCH], btp[SCH];
    #pragma unroll
    for (int s = 0; s < SCH; s++) {
      float vv = vbuf[cb][s * 16 + lcol];
      float bb = bbuf[c * SCH + s];
      btp[s] = bb;
      vbt[s] = vv * bb;
    }
    // register-rotate: load step s+1 (raw) while computing step s
    u32x4 kr = *(const u32x4*)(kcp + i * 8);
    u32x4 qr = *(const u32x4*)(qcp + i * 8);
    f32x4 g0 = *(const f32x4*)(gcp + i * 8), g1 = *(const f32x4*)(gcp + i * 8 + 4);
    #pragma unroll
    for (int s = 0; s < SCH; s++) {
      u32x4 krn, qrn; f32x4 g0n, g1n;
      if (s + 1 < SCH) {
        krn = *(const u32x4*)(kcp + (s + 1) * 128 + i * 8);
        qrn = *(const u32x4*)(qcp + (s + 1) * 128 + i * 8);
        g0n = *(const f32x4*)(gcp + (s + 1) * 128 + i * 8);
        g1n = *(const f32x4*)(gcp + (s + 1) * 128 + i * 8 + 4);
      }
      f32x4 k0, k1, q0, q1;
      unpack8(kr, k0, k1);
      unpack8(qr, q0, q1);
      // p = k . (S*g) = (k*g) . S_old  -- decay off the critical path
      f32x4 kg0 = k0 * g0, kg1 = k1 * g1;
      f32x4 pp = kg0 * s0 + kg1 * s1;
      float p = (pp[0] + pp[1]) + (pp[2] + pp[3]);
      p = reduce16(p);
      s0 *= g0; s1 *= g1;
      float u = fmaf(-btp[s], p, vbt[s]);    // u = (v - p)*beta
      s0 += k0 * u; s1 += k1 * u;
      f32x4 oo = q0 * s0 + q1 * s1;          // q pre-scaled by 128^-0.5
      float po = (oo[0] + oo[1]) + (oo[2] + oo[3]);
      po = reduce16(po);
      okeep = (i == s) ? po : okeep;         // cndmask, no divergence
      if (s + 1 < SCH) { kr = krn; qr = qrn; g0 = g0n; g1 = g1n; }
    }
    obh[((size_t)c * SCH + i) * 128 + col] = okeep;
    __syncthreads();
  }
}

// ---------------- gated RMSNorm -> bf16 (o f32 scan layout; gate bf16 row layout) ----------------
__global__ __launch_bounds__(256) void out_norm_kernel(const float* __restrict__ o,
                                                       const unsigned short* __restrict__ gate,
                                                       const float* __restrict__ w,
                                                       unsigned short* __restrict__ onb) {
  int bt = blockIdx.x, tid = threadIdx.x;
  int b = bt >> 11, t = bt & (TT - 1);
  int h = tid >> 4, seg = tid & 15;
  size_t obase = (((size_t)(b * HH + h)) * TT + t) * 128 + seg * 8;
  size_t gbase = (size_t)bt * HD + (size_t)h * 128 + seg * 8;
  f32x4 o0 = *(const f32x4*)(o + obase);
  f32x4 o1 = *(const f32x4*)(o + obase + 4);
  u32x4 graw = *(const u32x4*)(gate + gbase);
  float gv[8];
  #pragma unroll
  for (int jj = 0; jj < 4; jj++) {
    gv[2 * jj]     = __uint_as_float(graw[jj] << 16);
    gv[2 * jj + 1] = __uint_as_float(graw[jj] & 0xffff0000u);
  }
  float ss = 0.f;
  #pragma unroll
  for (int j = 0; j < 4; j++) ss += o0[j] * o0[j] + o1[j] * o1[j];
  ss = reduce16(ss);
  float rs = rsqrtf(ss * (1.f / 128.f) + 1e-5f);
  u16x4 r0, r1;
  #pragma unroll
  for (int j = 0; j < 4; j++) {
    float gv0 = gv[j];
    float gv1 = gv[4 + j];
    float a0 = o0[j] * rs * w[seg * 8 + j] * (gv0 / (1.f + expf(-gv0)));
    float a1 = o1[j] * rs * w[seg * 8 + 4 + j] * (gv1 / (1.f + expf(-gv1)));
    r0[j] = f2b(a0);
    r1[j] = f2b(a1);
  }
  *(u16x4*)(onb + gbase) = r0;
  *(u16x4*)(onb + gbase + 4) = r1;
}

// ---------------- driver ----------------
// Workspace (MB offsets, high-water 163.25):
//   [0,32)    WT     bf16 W^T: q|k|v|gate fused (32MB); later reused Wo
//   [32,48)   xb     bf16 x -> after qkvg gemm: qc16 (conv q output, bf16 scan)
//   [48,80)   geb    f32 decay, scan layout (written by gemm_gexp)
//   [80,96)   B1     bf16 q-pre -> after conv q: (part of) ob
//   [96,112)  B2     bf16 k-pre -> after conv k: (part of) ob  [ob = f32, 80..112)
//   [112,128) B3     bf16 v-pre -> after conv v: onb (out_norm output)
//   [128,144) gateb  bf16 row layout
//   [144,160) kc16   bf16 scan layout
//   [160,176) vc/ob? -> NO: vc f32 lives at [80,112) over dead B1,B2
//   [160,162) f1 | [162,163) f1b | [163,163.25) betab
extern "C" void kernel_launch(void* const* d_in, const int* in_sizes, int n_in,
                              void* d_out, int out_size, void* d_ws, size_t ws_size,
                              hipStream_t stream) {
  const float* x       = (const float*)d_in[0];
  const float* Wq      = (const float*)d_in[1];
  const float* Wk      = (const float*)d_in[2];
  const float* Wv      = (const float*)d_in[3];
  const float* cq      = (const float*)d_in[4];
  const float* ck      = (const float*)d_in[5];
  const float* cv      = (const float*)d_in[6];
  const float* Wf1     = (const float*)d_in[7];
  const float* Wf2     = (const float*)d_in[8];
  const float* Wb      = (const float*)d_in[9];
  const float* A_log   = (const float*)d_in[10];
  const float* dt_bias = (const float*)d_in[11];
  const float* Wg      = (const float*)d_in[12];
  const float* bg      = (const float*)d_in[13];
  const float* onw     = (const float*)d_in[14];
  const float* Wo      = (const float*)d_in[15];
  float* out = (float*)d_out;

  char* ws = (char*)d_ws;
  unsigned short* WT    = (unsigned short*)(ws);
  unsigned short* xb    = (unsigned short*)(ws + ((size_t)32 << 20));
  float* geb            = (float*)(ws + ((size_t)48 << 20));
  unsigned short* B1    = (unsigned short*)(ws + ((size_t)80 << 20));
  unsigned short* B2    = (unsigned short*)(ws + ((size_t)96 << 20));
  unsigned short* B3    = (unsigned short*)(ws + ((size_t)112 << 20));
  unsigned short* gateb = (unsigned short*)(ws + ((size_t)128 << 20));
  unsigned short* kc16  = (unsigned short*)(ws + ((size_t)144 << 20));
  float* f1             = (float*)(ws + ((size_t)160 << 20));
  unsigned short* f1b   = (unsigned short*)(ws + ((size_t)162 << 20));
  float* betab          = (float*)(ws + ((size_t)163 << 20));
  unsigned short* qc16  = xb;                              // xb dead after gemms
  float* vc             = (float*)(ws + ((size_t)80 << 20)); // over dead B1,B2
  float* ob             = vc;                              // scan o aliases v
  unsigned short* onb   = B3;                              // dead after conv v

  dim3 tb(32, 8);

  // 1. x -> bf16
  cast_f32_bf16<<<(MM * DD / 4 + 255) / 256, 256, 0, stream>>>(x, xb, MM * DD / 4);

  // 2. g chain: f1 = x@Wf1; geb = gexp(f1@Wf2) fused in epilogue
  transpose_cast<<<dim3(128 / 32, DD / 32), tb, 0, stream>>>(Wf1, WT, DD, 128);
  gemm_bf16<<<dim3(1, MM / 128), 256, 0, stream>>>(xb, WT, f1, nullptr, MM, 128, DD);
  cast_f32_bf16<<<(MM * 128 / 4 + 255) / 256, 256, 0, stream>>>(f1, f1b, MM * 128 / 4);
  transpose_cast<<<dim3(HD / 32, 128 / 32), tb, 0, stream>>>(Wf2, WT, 128, HD);
  gemm_gexp<<<dim3(HD / 128, MM / 128), 256, 0, stream>>>(f1b, WT, geb, A_log, dt_bias,
                                                          MM, HD, 128);

  // 3. beta
  beta_kernel<<<MM, 256, 0, stream>>>(x, Wb, betab);

  // 4. fused q|k|v|gate weights -> WT rows [0,2048) [2048,4096) [4096,6144) [6144,8192)
  transpose_cast<<<dim3(HD / 32, DD / 32), tb, 0, stream>>>(Wq, WT, DD, HD);
  transpose_cast<<<dim3(HD / 32, DD / 32), tb, 0, stream>>>(Wk, WT + (size_t)2048 * 2048, DD, HD);
  transpose_cast<<<dim3(HD / 32, DD / 32), tb, 0, stream>>>(Wv, WT + (size_t)4096 * 2048, DD, HD);
  transpose_cast<<<dim3(HD / 32, DD / 32), tb, 0, stream>>>(Wg, WT + (size_t)6144 * 2048, DD, HD);

  // 5. ONE fused GEMM N=8192 (2048 tiles = 8/CU)
  gemm_qkvg<<<dim3(8192 / 128, MM / 128), 256, 0, stream>>>(xb, WT, B1, B2, B3,
                                                            gateb, bg, MM, 8192, DD);

  // 6. convs: q,k -> bf16 scan layout; v -> f32 (over dead B1,B2)
  conv_silu_kernel<<<MM, 256, 0, stream>>>(B1, cq, qc16, 1, 0.08838834764831845f, 1);
  conv_silu_kernel<<<MM, 256, 0, stream>>>(B2, ck, kc16, 1, 1.0f, 1);
  conv_silu_kernel<<<MM, 256, 0, stream>>>(B3, cv, vc,   0, 1.0f, 0);

  // 7. delta-rule scan (bf16 q,k; f32 g,v; o aliases v)
  scan_kernel<<<BB * HH * 8, 256, 0, stream>>>(qc16, kc16, vc, geb, betab, ob);

  // 8. gated RMSNorm -> bf16 (onb over dead B3)
  out_norm_kernel<<<MM, 256, 0, stream>>>(ob, gateb, onw, onb);

  // 9. final projection
  transpose_cast<<<dim3(DD / 32, HD / 32), tb, 0, stream>>>(Wo, WT, HD, DD);
  gemm_bf16<<<dim3(DD / 128, MM / 128), 256, 0, stream>>>(onb, WT, out, nullptr, MM, DD, HD);
}